// Round 3
// baseline (349.867 us; speedup 1.0000x reference)
//
#include <hip/hip_runtime.h>

typedef unsigned int u32;
typedef unsigned long long u64;

// ---------------------------------------------------------------------------
// Exact reproduction of:
//   u    = jax.random.uniform(jax.random.key(42), (256,1024,256))   [threefry2x32]
//   rank = argsort(argsort(u, -1), -1)            (stable -> rank with index ties)
//   n1   = round_half_even(x * 256)
//   out  = (rank < n1) ? 1.0f : 0.0f
//
// PRNG layout — LAYOUT 2: jax_threefry_partitionable=True 32-bit path
// (_threefry_random_bits_partitionable):
//   counts1, counts2 = iota_2x32_shape(shape)     # (hi, lo) of flat idx; hi=0 here
//   bits1, bits2 = threefry2x32(key, counts)
//   bits32 = bits1 ^ bits2                        # <-- XOR of both output words
// History: LAYOUT 0 (word1 of (0,i)) FAILED r0; LAYOUT 1 (legacy split-iota
// word concat) FAILED r1. Selection/tie/rounding logic proven correct by hand.
// Ordering of u is ordering of m = bits32>>9 (u = m * 2^-23 exactly); ties on m.
// ---------------------------------------------------------------------------

__device__ __forceinline__ u32 rotl32(u32 x, int r) {
  return (x << r) | (x >> (32 - r));   // -> v_alignbit_b32
}

// Threefry-2x32, 20 rounds, key (0, 42). Block (0, i). Returns w0 ^ w1.
__device__ __forceinline__ u32 threefry_xor(u32 i) {
  const u32 ks0 = 0u;
  const u32 ks1 = 42u;
  const u32 ks2 = 0x1BD11BF0u;   // 0x1BD11BDA ^ 0 ^ 42
  u32 x0 = 0u + ks0;             // count_hi = 0
  u32 x1 = i + ks1;              // count_lo = flat element index
#define TFR(r) { x0 += x1; x1 = rotl32(x1, (r)); x1 ^= x0; }
  TFR(13) TFR(15) TFR(26) TFR(6)
  x0 += ks1; x1 += ks2 + 1u;
  TFR(17) TFR(29) TFR(16) TFR(24)
  x0 += ks2; x1 += ks0 + 2u;
  TFR(13) TFR(15) TFR(26) TFR(6)
  x0 += ks0; x1 += ks1 + 3u;
  TFR(17) TFR(29) TFR(16) TFR(24)
  x0 += ks1; x1 += ks2 + 4u;
  TFR(13) TFR(15) TFR(26) TFR(6)
  x0 += ks2; x1 += ks0 + 5u;
#undef TFR
  return x0 ^ x1;
}

__device__ __forceinline__ u32 rand23(u32 i) {
  return threefry_xor(i) >> 9;
}

__device__ __forceinline__ int mbcnt64(u64 m) {
  // popcount of mask bits strictly below this lane
  return (int)__builtin_amdgcn_mbcnt_hi((u32)(m >> 32),
              __builtin_amdgcn_mbcnt_lo((u32)m, 0u));
}

// One wave64 per bitstream row of 256 bits; lane owns bits b = 4*lane + {0..3}.
__global__ __launch_bounds__(256) void bitinput_kernel(
    const float* __restrict__ x, float* __restrict__ out, int nrows) {
  const int lane = threadIdx.x & 63;
  const int wid  = threadIdx.x >> 6;
  const int row  = (blockIdx.x << 2) + wid;
  if (row >= nrows) return;

  const float xe = x[row];                 // wave-uniform broadcast load
  const u32 base = ((u32)row) << 8;        // row * 256 (flat element index)
  const u32 ci   = base + ((u32)lane << 2);

  // ---- PRNG: 4 independent chains (good ILP), keep top-23 bits ----
  u32 v0 = rand23(ci + 0u);
  u32 v1 = rand23(ci + 1u);
  u32 v2 = rand23(ci + 2u);
  u32 v3 = rand23(ci + 3u);

  // n1 = round-half-even(x*256); x*256 is exact in f32
  const int n1 = __builtin_amdgcn_readfirstlane((int)rintf(xe * 256.0f));

  // ---- radix binary search for T = (n1-1)-th order statistic ----
  // invariant: count_less(T) = L <= n1-1; early exit on clean cut (cnt==n1)
  u32 T = 0u;
  int  L = 0;
  for (int bit = 22; bit >= 0; --bit) {
    const u32 mid = T | (1u << bit);
    const int cnt = __popcll(__ballot(v0 < mid)) + __popcll(__ballot(v1 < mid))
                  + __popcll(__ballot(v2 < mid)) + __popcll(__ballot(v3 < mid));
    if (cnt == n1) { T = mid; L = cnt; break; }  // exactly n1 below mid: done
    if (cnt <  n1) { T = mid; L = cnt; }
  }
  const int E = n1 - L;  // how many ties at T to include (index order); 0 if clean

  // ---- stable tie handling: include first E elements equal to T by index ----
  const int p0 = (v0 == T), p1 = (v1 == T), p2 = (v2 == T), p3 = (v3 == T);
  const u64 m0 = __ballot(p0), m1 = __ballot(p1);
  const u64 m2 = __ballot(p2), m3 = __ballot(p3);
  // #equal elements at indices with lane' < lane (same for all 4 slots, since
  // slot-minor layout b = 4*lane + k)
  const int S = mbcnt64(m0) + mbcnt64(m1) + mbcnt64(m2) + mbcnt64(m3);

  float4 o;
  o.x = (v0 < T || (p0 && (S               ) < E)) ? 1.0f : 0.0f;
  o.y = (v1 < T || (p1 && (S + p0          ) < E)) ? 1.0f : 0.0f;
  o.z = (v2 < T || (p2 && (S + p0 + p1     ) < E)) ? 1.0f : 0.0f;
  o.w = (v3 < T || (p3 && (S + p0 + p1 + p2) < E)) ? 1.0f : 0.0f;

  // lane writes 16B contiguous; wave covers the full 1KB row
  reinterpret_cast<float4*>(out)[(int)(base >> 2) + lane] = o;
}

extern "C" void kernel_launch(void* const* d_in, const int* in_sizes, int n_in,
                              void* d_out, int out_size, void* d_ws, size_t ws_size,
                              hipStream_t stream) {
  const float* x = (const float*)d_in[0];
  float* out = (float*)d_out;
  const int nrows = in_sizes[0];                 // 256*1024 = 262144 bitstreams
  const int blocks = (nrows + 3) >> 2;           // 4 waves (rows) per block
  hipLaunchKernelGGL(bitinput_kernel, dim3(blocks), dim3(256), 0, stream,
                     x, out, nrows);
}